// Round 17
// baseline (319.075 us; speedup 1.0000x reference)
//
#include <hip/hip_runtime.h>
#include <hip/hip_bf16.h>

// Problem constants
#define T_TOK 2048      // B*S
#define DDIM  1024
#define EEXP  8
#define KTOP  2
#define HDIM  2816
#define HSDIM 1536
#define BK    64
#define MT    128       // GEMM m-tile
#define NB_UP 22        // HDIM/128
#define NB_DN 8         // DDIM/128
#define RT_MAX 40       // max routed tiles: sum ceil(Ne/128) <= 32+7
#define GRID_P2UP (NB_UP * RT_MAX)        // 880
#define GRID_P2   (GRID_P2UP + 128)       // + shared-down riders
#define GRID_P3   (NB_DN * RT_MAX)        // 320

typedef float f32x4 __attribute__((ext_vector_type(4)));
typedef short bf16x8 __attribute__((ext_vector_type(8)));

__device__ __forceinline__ unsigned short f2bf(float f) {
    __hip_bfloat16 h = __float2bfloat16(f);
    return __builtin_bit_cast(unsigned short, h);
}

// async global->LDS, 16B per lane; LDS dest = wave-uniform base + lane*16
__device__ __forceinline__ void gload16(const void* g, void* l) {
    __builtin_amdgcn_global_load_lds(
        (const __attribute__((address_space(1))) unsigned int*)g,
        (__attribute__((address_space(3))) unsigned int*)l, 16, 0, 0);
}

// Bijective chunked XCD remap over a RUNTIME live count (m204 general form).
__device__ __forceinline__ int xcd_live_map(int i, int n) {
    int q = n >> 3, r = n & 7;
    int xcd = i & 7, loc = i >> 3;
    int cap = q + (xcd < r ? 1 : 0);
    if (loc >= cap) return -1;
    return (xcd < r ? xcd * (q + 1) : r * (q + 1) + (xcd - r) * q) + loc;
}

// ---------------- small routing kernels ----------------

__global__ void init_k(int* counts, int* cursors) {
    if (threadIdx.x < EEXP) { counts[threadIdx.x] = 0; cursors[threadIdx.x] = 0; }
}

__global__ void gate_k(const float* __restrict__ X, const float* __restrict__ GW,
                       int* __restrict__ topi, float* __restrict__ topw,
                       int* __restrict__ counts) {
    int lane = threadIdx.x & 63;
    int t = blockIdx.x * 4 + (threadIdx.x >> 6);
    int e  = lane >> 3;
    int c8 = lane & 7;
    const float* xr = X + (size_t)t * DDIM;
    const float* gr = GW + (size_t)e * DDIM;
    float acc = 0.f;
#pragma unroll 8
    for (int j = 0; j < 32; j++) {
        int d = (c8 + 8 * j) * 4;
        float4 xv = *(const float4*)(xr + d);
        float4 gv = *(const float4*)(gr + d);
        acc += xv.x * gv.x + xv.y * gv.y + xv.z * gv.z + xv.w * gv.w;
    }
    acc += __shfl_xor(acc, 1);
    acc += __shfl_xor(acc, 2);
    acc += __shfl_xor(acc, 4);
    float p[8];
#pragma unroll
    for (int q = 0; q < 8; q++) p[q] = __shfl(acc, q * 8);
    float mx = p[0];
#pragma unroll
    for (int q = 1; q < 8; q++) mx = fmaxf(mx, p[q]);
    float s = 0.f;
#pragma unroll
    for (int q = 0; q < 8; q++) { p[q] = expf(p[q] - mx); s += p[q]; }
    float inv = 1.f / s;
#pragma unroll
    for (int q = 0; q < 8; q++) p[q] *= inv;
    float v1 = -1.f; int i1 = 0;
#pragma unroll
    for (int q = 0; q < 8; q++) { if (p[q] > v1) { v1 = p[q]; i1 = q; } }
    float v2 = -1.f; int i2 = 0;
#pragma unroll
    for (int q = 0; q < 8; q++) { if (q != i1 && p[q] > v2) { v2 = p[q]; i2 = q; } }
    if (lane == 0) {
        topi[2 * t] = i1; topi[2 * t + 1] = i2;
        topw[2 * t] = v1; topw[2 * t + 1] = v2;
        atomicAdd(&counts[i1], 1);
        atomicAdd(&counts[i2], 1);
    }
}

// prefix-sum + device-built ROUTED tile worklist: (e<<16)|m0. wl_n[1]=count.
__global__ void scan_k(const int* __restrict__ counts, int* __restrict__ offsets,
                       int* __restrict__ wl, int* __restrict__ wl_n) {
    if (threadIdx.x == 0) {
        int s = 0;
        for (int e = 0; e < EEXP; e++) { offsets[e] = s; s += counts[e]; }
        offsets[EEXP] = s;
        int n = 0;
        for (int e = 0; e < EEXP; e++) {
            int Ne = counts[e];
            for (int m0 = 0; m0 < Ne; m0 += MT) wl[n++] = (e << 16) | m0;
        }
        wl_n[1] = n;                       // routed tile count (<= 40)
        wl_n[0] = n;
    }
}

__global__ void build_k(const int* __restrict__ topi, const float* __restrict__ topw,
                        const int* __restrict__ offsets,
                        int* __restrict__ cursors, int* __restrict__ rows_token,
                        float* __restrict__ gate_row) {
    int t = blockIdx.x * 256 + threadIdx.x;
    if (t >= T_TOK) return;
    for (int k = 0; k < KTOP; k++) {
        int e = topi[2 * t + k];
        int pos = atomicAdd(&cursors[e], 1);
        int r = offsets[e] + pos;
        rows_token[r] = t;
        gate_row[r] = topw[2 * t + k];
    }
}

// ---------------- tcast tile (R12-proven, 0 conflicts) ----------------
// Chunked transposed-weight layout: Wt_c[(kb*Nn+n)*32 + c4*8 + e] = bf16(W[k][n])
__device__ __forceinline__ void tcast_tile(const float* __restrict__ S,
                                           unsigned short* __restrict__ Dc,
                                           int Nn, int k0, int n0,
                                           float* __restrict__ ld /*[32*256]*/) {
    int tid = threadIdx.x, lane = tid & 63, w = tid >> 6;
#pragma unroll
    for (int j = 0; j < 8; j++) {
        int r = j * 4 + w;
        int f = ((r >> 3) & 3) << 2;
        gload16(S + (size_t)(k0 + r) * Nn + n0 + (lane ^ f) * 4, ld + r * 256);
    }
    __syncthreads();
    int c4 = tid & 3, nq = tid >> 2;
    int f  = c4 << 2;
    f32x4 blk[8];
#pragma unroll
    for (int jj = 0; jj < 8; jj++)
        blk[jj] = *(const f32x4*)(ld + (c4 * 8 + jj) * 256 + ((nq ^ f) & 63) * 4);
    size_t kb = (size_t)(k0 >> 5);
#pragma unroll
    for (int v = 0; v < 4; v++) {
        unsigned short o[8];
#pragma unroll
        for (int jj = 0; jj < 8; jj++) o[jj] = f2bf(blk[jj][v]);
        *(uint4*)(Dc + (kb * Nn + n0 + nq * 4 + v) * 32 + c4 * 8) = *(const uint4*)o;
    }
}

// ---------------- GEMM bodies (R12-proven, 256 thr, 128x128 tile) ----------------
// up: H = silu(A@W1) * (A@W3); rows_token==null -> identity rows (shared expert)
__device__ __forceinline__ void up_gemm_body(
    const unsigned short* __restrict__ Xb,
    const int* rows_token, int roff,
    const unsigned short* __restrict__ w1c,
    const unsigned short* __restrict__ w3c,
    unsigned short* __restrict__ Ho, int Nn,
    int m0, int n0, int Ne,
    unsigned short* As, unsigned short* B1s, unsigned short* B3s)
{
    int tid = threadIdx.x, lane = tid & 63, wid = tid >> 6;
    int wr = wid >> 1, wc = wid & 1;
    int cl = (lane & 7) ^ (lane >> 3);
    size_t bstep = (size_t)64 * Nn;
    const unsigned short* pA[4];
    const unsigned short *pB1[4], *pB3[4];
#pragma unroll
    for (int j = 0; j < 4; j++) {
        int lr = (wid * 4 + j) * 8 + (lane >> 3);
        int gr = m0 + lr; if (gr >= Ne) gr = Ne - 1;
        int tok = rows_token ? rows_token[roff + gr] : gr;
        pA[j]  = Xb + (size_t)tok * DDIM + cl * 8;
        size_t boff = ((size_t)(cl >> 2) * Nn + n0 + lr) * 32 + (cl & 3) * 8;
        pB1[j] = w1c + boff;
        pB3[j] = w3c + boff;
    }
    const f32x4 fz = {0.f, 0.f, 0.f, 0.f};
    f32x4 acc1[4][4], acc3[4][4];
#pragma unroll
    for (int mi = 0; mi < 4; mi++)
#pragma unroll
        for (int nj = 0; nj < 4; nj++) { acc1[mi][nj] = fz; acc3[mi][nj] = fz; }
#pragma unroll 1
    for (int ks = 0; ks < DDIM / BK; ks++) {
        __syncthreads();
#pragma unroll
        for (int j = 0; j < 4; j++) gload16(pA[j],  As  + (wid * 4 + j) * 512);
#pragma unroll
        for (int j = 0; j < 4; j++) gload16(pB1[j], B1s + (wid * 4 + j) * 512);
#pragma unroll
        for (int j = 0; j < 4; j++) gload16(pB3[j], B3s + (wid * 4 + j) * 512);
#pragma unroll
        for (int j = 0; j < 4; j++) { pA[j] += BK; pB1[j] += bstep; pB3[j] += bstep; }
        __syncthreads();
        int r = lane & 15, h = lane >> 4, sw = (lane & 7) << 4;
#pragma unroll
        for (int kk = 0; kk < 2; kk++) {
            int cb = (kk * 64 + h * 16) ^ sw;
            bf16x8 a[4], b1[4], b3[4];
#pragma unroll
            for (int mi = 0; mi < 4; mi++)
                a[mi] = *(const bf16x8*)((const char*)As + (wr * 64 + mi * 16 + r) * 128 + cb);
#pragma unroll
            for (int nj = 0; nj < 4; nj++) {
                b1[nj] = *(const bf16x8*)((const char*)B1s + (wc * 64 + nj * 16 + r) * 128 + cb);
                b3[nj] = *(const bf16x8*)((const char*)B3s + (wc * 64 + nj * 16 + r) * 128 + cb);
            }
#pragma unroll
            for (int mi = 0; mi < 4; mi++)
#pragma unroll
                for (int nj = 0; nj < 4; nj++) {
                    acc1[mi][nj] = __builtin_amdgcn_mfma_f32_16x16x32_bf16(a[mi], b1[nj], acc1[mi][nj], 0, 0, 0);
                    acc3[mi][nj] = __builtin_amdgcn_mfma_f32_16x16x32_bf16(a[mi], b3[nj], acc3[mi][nj], 0, 0, 0);
                }
        }
    }
    int r = lane & 15, h = lane >> 4;
#pragma unroll
    for (int mi = 0; mi < 4; mi++) {
#pragma unroll
        for (int nj = 0; nj < 4; nj++) {
            int col = n0 + wc * 64 + nj * 16 + r;
#pragma unroll
            for (int j = 0; j < 4; j++) {
                int row = wr * 64 + mi * 16 + h * 4 + j;
                if (m0 + row < Ne) {
                    float aa = acc1[mi][nj][j], bb = acc3[mi][nj][j];
                    float hv = (aa / (1.f + expf(-aa))) * bb;
                    Ho[(size_t)(roff + m0 + row) * Nn + col] = f2bf(hv);
                }
            }
        }
    }
}

// down: Y = A @ W2; rtok==null -> shared (direct store, row==token, g=1);
// else gated atomicAdd (out pre-zeroed / pre-filled by shared).
__device__ __forceinline__ void down_gemm_body(
    const unsigned short* __restrict__ Ab, int Kd,
    const unsigned short* __restrict__ Bb,
    int m0, int n0, int Ne,
    const int* rtok, const float* grow,
    float* __restrict__ out,
    unsigned short* As, unsigned short* Bs)
{
    int tid = threadIdx.x, lane = tid & 63, wid = tid >> 6;
    int wr = wid >> 1, wc = wid & 1;
    int cl = (lane & 7) ^ (lane >> 3);
    const size_t bstep = (size_t)64 * DDIM;
    const unsigned short* pA[4];
    const unsigned short* pB[4];
#pragma unroll
    for (int j = 0; j < 4; j++) {
        int lr = (wid * 4 + j) * 8 + (lane >> 3);
        int gr = m0 + lr; if (gr >= Ne) gr = Ne - 1;
        pA[j] = Ab + (size_t)gr * Kd + cl * 8;
        pB[j] = Bb + ((size_t)(cl >> 2) * DDIM + n0 + lr) * 32 + (cl & 3) * 8;
    }
    const f32x4 fz = {0.f, 0.f, 0.f, 0.f};
    f32x4 acc[4][4];
#pragma unroll
    for (int mi = 0; mi < 4; mi++)
#pragma unroll
        for (int nj = 0; nj < 4; nj++) acc[mi][nj] = fz;
    int nks = Kd / BK;
#pragma unroll 1
    for (int ks = 0; ks < nks; ks++) {
        __syncthreads();
#pragma unroll
        for (int j = 0; j < 4; j++) gload16(pA[j], As + (wid * 4 + j) * 512);
#pragma unroll
        for (int j = 0; j < 4; j++) gload16(pB[j], Bs + (wid * 4 + j) * 512);
#pragma unroll
        for (int j = 0; j < 4; j++) { pA[j] += BK; pB[j] += bstep; }
        __syncthreads();
        int r = lane & 15, h = lane >> 4, sw = (lane & 7) << 4;
#pragma unroll
        for (int kk = 0; kk < 2; kk++) {
            int cb = (kk * 64 + h * 16) ^ sw;
            bf16x8 a[4], b[4];
#pragma unroll
            for (int mi = 0; mi < 4; mi++)
                a[mi] = *(const bf16x8*)((const char*)As + (wr * 64 + mi * 16 + r) * 128 + cb);
#pragma unroll
            for (int nj = 0; nj < 4; nj++)
                b[nj] = *(const bf16x8*)((const char*)Bs + (wc * 64 + nj * 16 + r) * 128 + cb);
#pragma unroll
            for (int mi = 0; mi < 4; mi++)
#pragma unroll
                for (int nj = 0; nj < 4; nj++)
                    acc[mi][nj] = __builtin_amdgcn_mfma_f32_16x16x32_bf16(a[mi], b[nj], acc[mi][nj], 0, 0, 0);
        }
    }
    int r = lane & 15, h = lane >> 4;
#pragma unroll
    for (int mi = 0; mi < 4; mi++) {
#pragma unroll
        for (int j = 0; j < 4; j++) {
            int row = wr * 64 + mi * 16 + h * 4 + j;
            if (m0 + row >= Ne) continue;
#pragma unroll
            for (int nj = 0; nj < 4; nj++) {
                int col = n0 + wc * 64 + nj * 16 + r;
                if (rtok) {
                    atomicAdd(out + (size_t)rtok[m0 + row] * DDIM + col,
                              grow[m0 + row] * acc[mi][nj][j]);
                } else {
                    out[(size_t)(m0 + row) * DDIM + col] = acc[mi][nj][j];
                }
            }
        }
    }
}

// ---------------- Launch A: xcast + shared-weight transposes ----------------
__global__ __launch_bounds__(256) void prep_small_k(
    const float* __restrict__ x,
    const float* __restrict__ sw1, const float* __restrict__ sw3,
    const float* __restrict__ sw2,
    unsigned short* __restrict__ Xb,
    unsigned short* __restrict__ sw1t, unsigned short* __restrict__ sw3t,
    unsigned short* __restrict__ sw2t)
{
    __shared__ __align__(16) float ld[32 * 256];
    int b = blockIdx.x;
    if (b >= 576) {
        int i = (b - 576) * 2048 + threadIdx.x * 8;
        float4 a = *(const float4*)(x + i);
        float4 c = *(const float4*)(x + i + 4);
        unsigned short o[8] = { f2bf(a.x), f2bf(a.y), f2bf(a.z), f2bf(a.w),
                                f2bf(c.x), f2bf(c.y), f2bf(c.z), f2bf(c.w) };
        *(uint4*)(Xb + i) = *(const uint4*)o;
        return;
    }
    if (b < 192)      tcast_tile(sw1, sw1t, HSDIM, (b / 6) * 32, (b % 6) * 256, ld);
    else if (b < 384) { int i2 = b - 192; tcast_tile(sw3, sw3t, HSDIM, (i2 / 6) * 32, (i2 % 6) * 256, ld); }
    else              { int i2 = b - 384; tcast_tile(sw2, sw2t, DDIM, (i2 / 4) * 32, (i2 % 4) * 256, ld); }
}

// ---------------- Launch B: W2/W1/W3 transposes + shared-up GEMM riders ----------------
__global__ __launch_bounds__(256, 2) void phase1_k(
    const float* __restrict__ w1, const float* __restrict__ w3,
    const float* __restrict__ w2,
    const unsigned short* __restrict__ Xb,
    const unsigned short* __restrict__ sw1t, const unsigned short* __restrict__ sw3t,
    unsigned short* __restrict__ W1t, unsigned short* __restrict__ W3t,
    unsigned short* __restrict__ W2t,
    unsigned short* __restrict__ Hs,
    int withW2)
{
    __shared__ __align__(16) unsigned short smem[3 * 128 * 64];   // 48 KB
    int b = blockIdx.x;
    const size_t DH = (size_t)DDIM * HDIM;
    if (b < 192) {
        // shared-expert up-GEMM rider: 16 m-tiles x 12 n-tiles
        up_gemm_body(Xb, nullptr, 0, sw1t, sw3t, Hs, HSDIM,
                     (b & 15) * 128, (b >> 4) * 128, T_TOK,
                     smem, smem + 8192, smem + 16384);
        return;
    }
    int b2 = b - 192;
    if (withW2) {
        if (b2 < 2816) {   // W2 FIRST (its f32 reads precede W1t/W3t L3 fill)
            int z = b2 / 352, r = b2 % 352;
            tcast_tile(w2 + z * DH, W2t + z * DH, DDIM,
                       (r / 4) * 32, (r % 4) * 256, (float*)smem);
            return;
        }
        b2 -= 2816;
    }
    if (b2 < 2816) {
        int z = b2 / 352, r = b2 % 352;
        tcast_tile(w1 + z * DH, W1t + z * DH, HDIM,
                   (r / 11) * 32, (r % 11) * 256, (float*)smem);
    } else {
        int i2 = b2 - 2816, z = i2 / 352, r = i2 % 352;
        tcast_tile(w3 + z * DH, W3t + z * DH, HDIM,
                   (r / 11) * 32, (r % 11) * 256, (float*)smem);
    }
}

// ---------------- Launch C: routed up-GEMM + shared-down riders ----------------
__global__ __launch_bounds__(256, 2) void phase2_k(
    const unsigned short* __restrict__ Xb,
    const int* __restrict__ rows_token,
    const int* __restrict__ offsets,
    const unsigned short* __restrict__ W1t, const unsigned short* __restrict__ W3t,
    unsigned short* __restrict__ Hg,
    const unsigned short* __restrict__ Hs,
    const unsigned short* __restrict__ sw2t,
    float* __restrict__ out,
    const int* __restrict__ wl, const int* __restrict__ wl_n)
{
    __shared__ __align__(16) unsigned short smem[3 * 128 * 64];   // 48 KB
    int b = blockIdx.x;
    if (b >= GRID_P2UP) {
        // shared-expert down-GEMM rider: 16 m x 8 n, direct store into out
        int idx = b - GRID_P2UP;
        down_gemm_body(Hs, HSDIM, sw2t, (idx & 15) * 128, (idx >> 4) * 128,
                       T_TOK, nullptr, nullptr, out, smem, smem + 8192);
        return;
    }
    int n_r = wl_n[1];
    int live = NB_UP * n_r;
    int L = xcd_live_map(b, live);
    if (L < 0 || L >= live) return;
    int nb = L / n_r, it = L % n_r;
    int pk = wl[it];
    int z = pk >> 16, m0 = pk & 0xffff;
    int roff = offsets[z], Ne = offsets[z + 1] - roff;
    up_gemm_body(Xb, rows_token, roff,
                 W1t + (size_t)z * HDIM * DDIM, W3t + (size_t)z * HDIM * DDIM,
                 Hg, HDIM, m0, nb * 128, Ne,
                 smem, smem + 8192, smem + 16384);
}

// ---------------- Launch D: routed down-GEMM + gated combine ----------------
__global__ __launch_bounds__(256, 2) void phase3_k(
    const unsigned short* __restrict__ Hg,
    const unsigned short* __restrict__ W2t,
    const int* __restrict__ offsets,
    const int* __restrict__ rows_token,
    const float* __restrict__ gate_row,
    float* __restrict__ out,
    const int* __restrict__ wl, const int* __restrict__ wl_n)
{
    __shared__ __align__(16) unsigned short smem[2 * 128 * 64];   // 32 KB
    int n_r = wl_n[1];
    int live = NB_DN * n_r;
    int L = xcd_live_map(blockIdx.x, live);
    if (L < 0 || L >= live) return;
    int nb = L / n_r, it = L % n_r;
    int pk = wl[it];
    int z = pk >> 16, m0 = pk & 0xffff;
    int roff = offsets[z], Ne = offsets[z + 1] - roff;
    down_gemm_body(Hg + (size_t)roff * HDIM, HDIM,
                   W2t + (size_t)z * (size_t)DDIM * HDIM,
                   m0, nb * 128, Ne,
                   rows_token + roff, gate_row + roff, out,
                   smem, smem + 8192);
}

// Fallback W2 transpose (aliased region) when workspace too small.
__global__ __launch_bounds__(256) void tcast_k(const float* __restrict__ S,
                                               unsigned short* __restrict__ Dm) {
    __shared__ __align__(16) float ld[32 * 256];
    int b = blockIdx.x;
    int z = b / 352, r = b % 352;
    size_t zo = (size_t)z * HDIM * DDIM;
    tcast_tile(S + zo, Dm + zo, DDIM, (r / 4) * 32, (r % 4) * 256, ld);
}

// ---------------- launch ----------------
extern "C" void kernel_launch(void* const* d_in, const int* in_sizes, int n_in,
                              void* d_out, int out_size, void* d_ws, size_t ws_size,
                              hipStream_t stream) {
    const float* x   = (const float*)d_in[0];
    const float* gw  = (const float*)d_in[1];
    const float* w1  = (const float*)d_in[2];
    const float* w3  = (const float*)d_in[3];
    const float* w2  = (const float*)d_in[4];
    const float* sw1 = (const float*)d_in[5];
    const float* sw3 = (const float*)d_in[6];
    const float* sw2 = (const float*)d_in[7];
    float* out = (float*)d_out;
    char* ws = (char*)d_ws;

    const size_t MB = 1048576;
    int*   counts     = (int*)(ws);
    int*   offsets    = (int*)(ws + 64);
    int*   cursors    = (int*)(ws + 128);
    int*   wl_n       = (int*)(ws + 192);     // [1]=routed tile count
    int*   wl         = (int*)(ws + 256);
    int*   topi       = (int*)(ws + 512);
    float* topw       = (float*)(ws + 16896);
    int*   rows_token = (int*)(ws + 33280);
    float* gate_row   = (float*)(ws + 49664);
    unsigned short* Xb   = (unsigned short*)(ws + 1 * MB);    // 4 MB
    unsigned short* sw1t = (unsigned short*)(ws + 6 * MB);    // 3 MB
    unsigned short* sw3t = (unsigned short*)(ws + 9 * MB);    // 3 MB
    unsigned short* sw2t = (unsigned short*)(ws + 12 * MB);   // 3 MB
    unsigned short* Hg   = (unsigned short*)(ws + 16 * MB);   // 22 MB
    unsigned short* Hs   = (unsigned short*)(ws + 40 * MB);   // 6 MB
    unsigned short* W1t  = (unsigned short*)(ws + 64 * MB);   // 44 MB
    unsigned short* W3t  = (unsigned short*)(ws + 108 * MB);  // 44 MB (ends 152 MB)

    bool sepW2 = (ws_size >= 196 * MB);
    unsigned short* W2t = sepW2 ? (unsigned short*)(ws + 152 * MB) : W1t;

    // routing
    init_k<<<1, 64, 0, stream>>>(counts, cursors);
    gate_k<<<T_TOK / 4, 256, 0, stream>>>(x, gw, topi, topw, counts);
    scan_k<<<1, 64, 0, stream>>>(counts, offsets, wl, wl_n);
    build_k<<<T_TOK / 256, 256, 0, stream>>>(topi, topw, offsets, cursors,
                                             rows_token, gate_row);

    // zero out (shared-down direct-stores, routed atomicAdds on top)
    hipMemsetAsync(out, 0, (size_t)T_TOK * DDIM * sizeof(float), stream);

    // A: xcast + shared-weight transposes (inputs for phase1 riders)
    prep_small_k<<<1600, 256, 0, stream>>>(x, sw1, sw3, sw2, Xb, sw1t, sw3t, sw2t);

    // B: big weight transposes + shared-up GEMM riders (-> Hs)
    phase1_k<<<192 + 2 * 2816 + (sepW2 ? 2816 : 0), 256, 0, stream>>>(
        w1, w3, w2, Xb, sw1t, sw3t, W1t, W3t, W2t, Hs, sepW2 ? 1 : 0);

    // C: routed up-GEMM (-> Hg) + shared-down riders (-> out direct)
    phase2_k<<<GRID_P2, 256, 0, stream>>>(
        Xb, rows_token, offsets, W1t, W3t, Hg, Hs, sw2t, out, wl, wl_n);

    // fallback W2 transpose (aliased over W1t, after phase2 consumed it)
    if (!sepW2)
        tcast_k<<<2816, 256, 0, stream>>>(w2, W2t);

    // D: routed down-GEMM + gated atomic combine
    phase3_k<<<GRID_P3, 256, 0, stream>>>(
        Hg, W2t, offsets, rows_token, gate_row, out, wl, wl_n);
}